// Round 5
// baseline (7321.821 us; speedup 1.0000x reference)
//
#include <hip/hip_runtime.h>
#include <hip/hip_bf16.h>

#define Vv 32000
#define Dm 768
#define Lm 4
#define Nst 16
#define Kc 4
#define Im 1536
#define DTr 48
#define Bt 4
#define Sq 2048
#define TOK (Bt*Sq)
#define EPSf 1e-5f

using bf16 = __hip_bfloat16;
typedef __bf16 bf16x8 __attribute__((ext_vector_type(8)));
typedef float f32x4 __attribute__((ext_vector_type(4)));

__device__ __forceinline__ float b2f(bf16 x){ return __bfloat162float(x); }
__device__ __forceinline__ bf16 f2b(float x){ return __float2bfloat16(x); }

// ---------------- f32 -> bf16 weight conversion (n multiple of 1024) --------
__global__ __launch_bounds__(256) void k_cvt(const float* __restrict__ src,
                                             bf16* __restrict__ dst, int n){
  int i = (blockIdx.x*256 + threadIdx.x)*4;
  if (i >= n) return;
  float4 v = *(const float4*)(src + i);
  bf16* o = dst + i;
  o[0]=f2b(v.x); o[1]=f2b(v.y); o[2]=f2b(v.z); o[3]=f2b(v.w);
}

// x_proj_w (L,80,Im) f32 -> (L,128,Im) bf16, rows 80..127 zero
__global__ __launch_bounds__(256) void k_cvt_xpw(const float* __restrict__ src,
                                                 bf16* __restrict__ dst){
  int idx = blockIdx.x*256 + threadIdx.x;        // over L*128*Im
  int l = idx / (128*Im); int rem = idx - l*128*Im;
  int r = rem / Im;       int c = rem - r*Im;
  dst[idx] = (r < 80) ? f2b(src[((size_t)l*80 + r)*Im + c]) : f2b(0.f);
}

// dt_proj_w (L,Im,48) f32 -> (L,Im,64) bf16, cols 48..63 zero
__global__ __launch_bounds__(256) void k_cvt_dtw(const float* __restrict__ src,
                                                 bf16* __restrict__ dst){
  int idx = blockIdx.x*256 + threadIdx.x;        // over L*Im*64
  int l = idx / (Im*64); int rem = idx - l*Im*64;
  int r = rem / 64;      int c = rem - r*64;
  dst[idx] = (c < 48) ? f2b(src[((size_t)l*Im + r)*48 + c]) : f2b(0.f);
}

// ---------------- embedding gather: h[t,:] = embed[ids[t],:] (f32) ----------
__global__ __launch_bounds__(256) void k_embed(const int* __restrict__ ids,
                                               const float* __restrict__ emb,
                                               float* __restrict__ h){
  int t = blockIdx.x;
  const float4* e = (const float4*)(emb + (size_t)ids[t]*Dm);
  float4* o = (float4*)(h + (size_t)t*Dm);
  if (threadIdx.x < Dm/4) o[threadIdx.x] = e[threadIdx.x];
}

// ---------------- rmsnorm over D=768, one block per token -------------------
__global__ __launch_bounds__(256) void k_rmsnorm(const float* __restrict__ h,
                                                 const float* __restrict__ w,
                                                 bf16* __restrict__ xb){
  int t = blockIdx.x;
  const float* x = h + (size_t)t*Dm;
  float v[3]; float ss = 0.f;
  #pragma unroll
  for (int j=0;j<3;j++){ v[j] = x[threadIdx.x + j*256]; ss += v[j]*v[j]; }
  #pragma unroll
  for (int off=32; off; off>>=1) ss += __shfl_xor(ss, off);
  __shared__ float sred[4];
  int wave = threadIdx.x>>6, lane = threadIdx.x&63;
  if (lane==0) sred[wave]=ss;
  __syncthreads();
  float tot = sred[0]+sred[1]+sred[2]+sred[3];
  float scale = rsqrtf(tot*(1.f/Dm) + EPSf);
  bf16* o = xb + (size_t)t*Dm;
  #pragma unroll
  for (int j=0;j<3;j++){ int d = threadIdx.x + j*256; o[d] = f2b(v[j]*scale*w[d]); }
}

// ---------------- final rmsnorm, last token per batch ------------------------
__global__ __launch_bounds__(256) void k_rms_last(const float* __restrict__ h,
                                                  const float* __restrict__ w,
                                                  float* __restrict__ xf){
  int b = blockIdx.x;
  const float* x = h + ((size_t)b*Sq + (Sq-1))*Dm;
  float v[3]; float ss = 0.f;
  #pragma unroll
  for (int j=0;j<3;j++){ v[j] = x[threadIdx.x + j*256]; ss += v[j]*v[j]; }
  #pragma unroll
  for (int off=32; off; off>>=1) ss += __shfl_xor(ss, off);
  __shared__ float sred[4];
  int wave = threadIdx.x>>6, lane = threadIdx.x&63;
  if (lane==0) sred[wave]=ss;
  __syncthreads();
  float tot = sred[0]+sred[1]+sred[2]+sred[3];
  float scale = rsqrtf(tot*(1.f/Dm) + EPSf);
  float* o = xf + (size_t)b*Dm;
  #pragma unroll
  for (int j=0;j<3;j++){ int d = threadIdx.x + j*256; o[d] = v[j]*scale*w[d]; }
}

// ---------------- MFMA bf16 GEMM: C(M,N) = A(M,K) * B(N,K)^T -----------------
// MODE 0: store bf16 | MODE 1: C_f32 += acc | MODE 3: f32 softplus(acc+bias[col])
template<int MODE>
__global__ __launch_bounds__(256) void k_gemm(const bf16* __restrict__ A,
                                              const bf16* __restrict__ Bw,
                                              void* __restrict__ Cout,
                                              const float* __restrict__ bias,
                                              int M, int N, int K,
                                              int lda, int ldb, int ldc){
  __shared__ __align__(16) ushort Ash[128*32];
  __shared__ __align__(16) ushort Bsh[128*32];
  int tid = threadIdx.x;
  int bm = blockIdx.y, bn = blockIdx.x;
  int wave = tid >> 6, lane = tid & 63;
  int wrow = wave >> 1, wcol = wave & 1;
  int quad = lane >> 4, lq = lane & 15;

  f32x4 acc[4][4];
  #pragma unroll
  for (int a=0;a<4;a++)
    #pragma unroll
    for (int b=0;b<4;b++) acc[a][b] = (f32x4){0.f,0.f,0.f,0.f};

  const ushort* Ag = (const ushort*)A;
  const ushort* Bg = (const ushort*)Bw;

  for (int k0 = 0; k0 < K; k0 += 32) {
    __syncthreads();
    #pragma unroll
    for (int c = tid; c < 512; c += 256) {
      int row = c >> 2, col = (c & 3) * 8;
      *(uint4*)&Ash[row*32 + col] = *(const uint4*)&Ag[(size_t)(bm*128 + row)*lda + k0 + col];
      *(uint4*)&Bsh[row*32 + col] = *(const uint4*)&Bg[(size_t)(bn*128 + row)*ldb + k0 + col];
    }
    __syncthreads();
    bf16x8 af[4], bfr[4];
    #pragma unroll
    for (int a=0;a<4;a++){
      int m = wrow*64 + a*16 + lq;
      af[a] = __builtin_bit_cast(bf16x8, *(const uint4*)&Ash[m*32 + quad*8]);
    }
    #pragma unroll
    for (int b=0;b<4;b++){
      int n = wcol*64 + b*16 + lq;
      bfr[b] = __builtin_bit_cast(bf16x8, *(const uint4*)&Bsh[n*32 + quad*8]);
    }
    #pragma unroll
    for (int a=0;a<4;a++)
      #pragma unroll
      for (int b=0;b<4;b++)
        acc[a][b] = __builtin_amdgcn_mfma_f32_16x16x32_bf16(af[a], bfr[b], acc[a][b], 0, 0, 0);
  }
  // C/D layout (HW-verified gfx950): row = quad*4+reg, col = lane&15
  #pragma unroll
  for (int a=0;a<4;a++)
    #pragma unroll
    for (int b=0;b<4;b++)
      #pragma unroll
      for (int r=0;r<4;r++){
        int row = bm*128 + wrow*64 + a*16 + quad*4 + r;
        int col = bn*128 + wcol*64 + b*16 + lq;
        size_t idx = (size_t)row*ldc + col;
        if (MODE == 0) ((bf16*)Cout)[idx] = f2b(acc[a][b][r]);
        else if (MODE == 1) ((float*)Cout)[idx] += acc[a][b][r];
        else {
          float v = acc[a][b][r] + bias[col];
          ((float*)Cout)[idx] = (v > 20.f) ? v : log1pf(__expf(v));
        }
      }
}

// ---------------- depthwise causal conv K=4 + bias + SiLU --------------------
__global__ __launch_bounds__(256) void k_conv(const bf16* __restrict__ proj,
                                              const float* __restrict__ cw,
                                              const float* __restrict__ cb,
                                              bf16* __restrict__ ut){
  int t = blockIdx.y;
  int i = blockIdx.x*256 + threadIdx.x;
  int s = t & (Sq-1);
  float acc = cb[i];
  #pragma unroll
  for (int k=0;k<Kc;k++){
    int sk = s + k - 3;
    if (sk >= 0) acc += b2f(proj[(size_t)(t+k-3)*(2*Im) + i]) * cw[i*Kc+k];
  }
  float sig = 1.f/(1.f+__expf(-acc));
  ut[(size_t)t*Im + i] = f2b(acc*sig);
}

// ---------------- selective scan: thread per (b,i,n), 16-lane reduce ---------
// epilogue fused: y = (scan_y + ut*D) * silu(gate), written bf16
__global__ __launch_bounds__(256) void k_scan(const float* __restrict__ dt,
                                              const bf16* __restrict__ ut,
                                              const bf16* __restrict__ xdbl,
                                              const bf16* __restrict__ proj,
                                              const float* __restrict__ alog,
                                              const float* __restrict__ dpar,
                                              bf16* __restrict__ y){
  int gtid = blockIdx.x*256 + threadIdx.x;
  int c = gtid >> 4;          // (b,i) channel
  int n = gtid & 15;
  int b = c / Im;
  int i = c - b*Im;
  float A = -__expf(alog[i*Nst + n]);
  float Dp = dpar[i];
  size_t tok0 = (size_t)b*Sq;
  const float* dtp = dt   + tok0*Im + i;
  const bf16*  utp = ut   + tok0*Im + i;
  const bf16*  Bp  = xdbl + tok0*128 + DTr + n;
  const bf16*  Cp  = Bp + Nst;
  const bf16*  gp  = proj + tok0*(2*Im) + Im + i;
  bf16* yp = y + tok0*Im + i;
  float h = 0.f;
  for (int t = 0; t < Sq; t++){
    float dtv = dtp[0];
    float uv  = b2f(utp[0]);
    float Bn = b2f(Bp[0]), Cn = b2f(Cp[0]);
    float dA = __expf(dtv*A);
    h = dA*h + dtv*uv*Bn;
    float p = h*Cn;
    p += __shfl_xor(p,1); p += __shfl_xor(p,2);
    p += __shfl_xor(p,4); p += __shfl_xor(p,8);
    if (n==0){
      float g = b2f(gp[0]);
      float yv = (p + uv*Dp) * (g/(1.f+__expf(-g)));
      yp[0] = f2b(yv);
    }
    dtp += Im; utp += Im; Bp += 128; Cp += 128; gp += 2*Im; yp += Im;
  }
}

// ---------------- logits (f32 out): out[b,v] = xf[b,:] . embed[v,:] ----------
__global__ __launch_bounds__(256) void k_logits(const float* __restrict__ xf,
                                                const float* __restrict__ emb,
                                                float* __restrict__ out){
  __shared__ __align__(16) float xs[Bt*Dm];
  for (int j = threadIdx.x; j < Bt*Dm; j += 256) xs[j] = xf[j];
  __syncthreads();
  int wave = threadIdx.x>>6, lane = threadIdx.x&63;
  int v = blockIdx.x*4 + wave;
  const float4* e4 = (const float4*)(emb + (size_t)v*Dm);
  float a0=0.f,a1=0.f,a2=0.f,a3=0.f;
  for (int j = lane; j < Dm/4; j += 64){
    float4 ev = e4[j];
    float4 x0 = *(const float4*)&xs[j*4];
    float4 x1 = *(const float4*)&xs[Dm + j*4];
    float4 x2 = *(const float4*)&xs[2*Dm + j*4];
    float4 x3 = *(const float4*)&xs[3*Dm + j*4];
    a0 += ev.x*x0.x + ev.y*x0.y + ev.z*x0.z + ev.w*x0.w;
    a1 += ev.x*x1.x + ev.y*x1.y + ev.z*x1.z + ev.w*x1.w;
    a2 += ev.x*x2.x + ev.y*x2.y + ev.z*x2.z + ev.w*x2.w;
    a3 += ev.x*x3.x + ev.y*x3.y + ev.z*x3.z + ev.w*x3.w;
  }
  #pragma unroll
  for (int off=32; off; off>>=1){
    a0+=__shfl_xor(a0,off); a1+=__shfl_xor(a1,off);
    a2+=__shfl_xor(a2,off); a3+=__shfl_xor(a3,off);
  }
  if (lane==0){
    out[v]        = a0;
    out[Vv+v]     = a1;
    out[2*Vv+v]   = a2;
    out[3*Vv+v]   = a3;
  }
}

extern "C" void kernel_launch(void* const* d_in, const int* in_sizes, int n_in,
                              void* d_out, int out_size, void* d_ws, size_t ws_size,
                              hipStream_t stream){
  const int*   ids   = (const int*)d_in[0];
  const float* emb   = (const float*)d_in[1];
  const float* normw = (const float*)d_in[2];
  const float* inw   = (const float*)d_in[3];
  const float* cw    = (const float*)d_in[4];
  const float* cb    = (const float*)d_in[5];
  const float* xpw   = (const float*)d_in[6];
  const float* dtw   = (const float*)d_in[7];
  const float* dtb   = (const float*)d_in[8];
  const float* alog  = (const float*)d_in[9];
  const float* dpar  = (const float*)d_in[10];
  const float* outw  = (const float*)d_in[11];
  const float* normf = (const float*)d_in[12];
  float* out = (float*)d_out;   // reference output dtype is float32

  char* p = (char*)d_ws;
  float* h    = (float*)p;  p += (size_t)TOK*Dm*4;        // 25.2 MB
  bf16*  xb   = (bf16*)p;   p += (size_t)TOK*Dm*2;        // 12.6 MB
  bf16*  proj = (bf16*)p;   p += (size_t)TOK*2*Im*2;      // 50.3 MB  (u | gate)
  bf16*  utb  = (bf16*)p;   p += (size_t)TOK*Im*2;        // 25.2 MB
  bf16*  xdbl = (bf16*)p;   p += (size_t)TOK*128*2;       // 2.1 MB   (dt_r|B|C|pad)
  float* dtf  = (float*)p;  p += (size_t)TOK*Im*4;        // 50.3 MB
  bf16*  yb   = (bf16*)p;   p += (size_t)TOK*Im*2;        // 25.2 MB
  float* xf   = (float*)p;  p += (size_t)Bt*Dm*4;         // 12 KB
  bf16*  inwb = (bf16*)p;   p += (size_t)Lm*2*Im*Dm*2;    // 18.9 MB
  bf16*  outwb= (bf16*)p;   p += (size_t)Lm*Dm*Im*2;      // 9.4 MB
  bf16*  xpwb = (bf16*)p;   p += (size_t)Lm*128*Im*2;     // 1.6 MB
  bf16*  dtwb = (bf16*)p;   p += (size_t)Lm*Im*64*2;      // 0.8 MB (~222 MB total, R2-proven)

  // weight conversions (every call — no static state)
  { int n = Lm*2*Im*Dm; k_cvt<<<n/1024, 256, 0, stream>>>(inw, inwb, n); }
  { int n = Lm*Dm*Im;   k_cvt<<<n/1024, 256, 0, stream>>>(outw, outwb, n); }
  k_cvt_xpw<<<(Lm*128*Im)/256, 256, 0, stream>>>(xpw, xpwb);
  k_cvt_dtw<<<(Lm*Im*64)/256, 256, 0, stream>>>(dtw, dtwb);

  k_embed<<<TOK, 256, 0, stream>>>(ids, emb, h);

  for (int l = 0; l < Lm; l++){
    k_rmsnorm<<<TOK, 256, 0, stream>>>(h, normw + l*Dm, xb);
    // in_proj: proj(TOK,3072) = xb(TOK,768) . inw(3072,768)^T
    k_gemm<0><<<dim3((2*Im)/128, TOK/128), 256, 0, stream>>>(
        xb, inwb + (size_t)l*2*Im*Dm, proj, nullptr, TOK, 2*Im, Dm, Dm, Dm, 2*Im);
    k_conv<<<dim3(Im/256, TOK), 256, 0, stream>>>(
        proj, cw + (size_t)l*Im*Kc, cb + (size_t)l*Im, utb);
    // x_proj: xdbl(TOK,128) = utb(TOK,1536) . xpwb(128,1536)^T (rows 80.. zero)
    k_gemm<0><<<dim3(1, TOK/128), 256, 0, stream>>>(
        utb, xpwb + (size_t)l*128*Im, xdbl, nullptr, TOK, 128, Im, Im, Im, 128);
    // dt_proj+softplus: dtf(TOK,1536) = xdbl(TOK,64) . dtwb(1536,64)^T + dtb
    // (xdbl cols 48..63 hold B, but dtwb cols 48..63 are zero -> no contribution)
    k_gemm<3><<<dim3(Im/128, TOK/128), 256, 0, stream>>>(
        xdbl, dtwb + (size_t)l*Im*64, dtf, dtb + (size_t)l*Im, TOK, Im, 64, 128, 64, Im);
    k_scan<<<(Bt*Im*Nst)/256, 256, 0, stream>>>(
        dtf, utb, xdbl, proj, alog + (size_t)l*Im*Nst, dpar + (size_t)l*Im, yb);
    // out_proj (+residual): h(TOK,768) += yb(TOK,1536) . outw(768,1536)^T
    k_gemm<1><<<dim3(Dm/128, TOK/128), 256, 0, stream>>>(
        yb, outwb + (size_t)l*Dm*Im, h, nullptr, TOK, Dm, Im, Im, Im, Dm);
  }

  k_rms_last<<<Bt, 256, 0, stream>>>(h, normf, xf);
  k_logits<<<Vv/4, 256, 0, stream>>>(xf, emb, out);
}

// Round 6
// 3408.621 us; speedup vs baseline: 2.1480x; 2.1480x over previous
//
#include <hip/hip_runtime.h>
#include <hip/hip_bf16.h>

#define Vv 32000
#define Dm 768
#define Lm 4
#define Nst 16
#define Kc 4
#define Im 1536
#define DTr 48
#define Bt 4
#define Sq 2048
#define TOK (Bt*Sq)
#define EPSf 1e-5f

using bf16 = __hip_bfloat16;
typedef __bf16 bf16x8 __attribute__((ext_vector_type(8)));
typedef float f32x4 __attribute__((ext_vector_type(4)));

__device__ __forceinline__ float b2f(bf16 x){ return __bfloat162float(x); }
__device__ __forceinline__ bf16 f2b(float x){ return __float2bfloat16(x); }

// ---------------- f32 -> bf16 weight conversion (n multiple of 1024) --------
__global__ __launch_bounds__(256) void k_cvt(const float* __restrict__ src,
                                             bf16* __restrict__ dst, int n){
  int i = (blockIdx.x*256 + threadIdx.x)*4;
  if (i >= n) return;
  float4 v = *(const float4*)(src + i);
  bf16* o = dst + i;
  o[0]=f2b(v.x); o[1]=f2b(v.y); o[2]=f2b(v.z); o[3]=f2b(v.w);
}

// x_proj_w (L,80,Im) f32 -> (L,128,Im) bf16, rows 80..127 zero
__global__ __launch_bounds__(256) void k_cvt_xpw(const float* __restrict__ src,
                                                 bf16* __restrict__ dst){
  int idx = blockIdx.x*256 + threadIdx.x;        // over L*128*Im
  int l = idx / (128*Im); int rem = idx - l*128*Im;
  int r = rem / Im;       int c = rem - r*Im;
  dst[idx] = (r < 80) ? f2b(src[((size_t)l*80 + r)*Im + c]) : f2b(0.f);
}

// dt_proj_w (L,Im,48) f32 -> (L,Im,64) bf16, cols 48..63 zero
__global__ __launch_bounds__(256) void k_cvt_dtw(const float* __restrict__ src,
                                                 bf16* __restrict__ dst){
  int idx = blockIdx.x*256 + threadIdx.x;        // over L*Im*64
  int l = idx / (Im*64); int rem = idx - l*Im*64;
  int r = rem / 64;      int c = rem - r*64;
  dst[idx] = (c < 48) ? f2b(src[((size_t)l*Im + r)*48 + c]) : f2b(0.f);
}

// ---------------- embedding gather: h[t,:] = embed[ids[t],:] (f32) ----------
__global__ __launch_bounds__(256) void k_embed(const int* __restrict__ ids,
                                               const float* __restrict__ emb,
                                               float* __restrict__ h){
  int t = blockIdx.x;
  const float4* e = (const float4*)(emb + (size_t)ids[t]*Dm);
  float4* o = (float4*)(h + (size_t)t*Dm);
  if (threadIdx.x < Dm/4) o[threadIdx.x] = e[threadIdx.x];
}

// ---------------- rmsnorm over D=768, one block per token -------------------
__global__ __launch_bounds__(256) void k_rmsnorm(const float* __restrict__ h,
                                                 const float* __restrict__ w,
                                                 bf16* __restrict__ xb){
  int t = blockIdx.x;
  const float* x = h + (size_t)t*Dm;
  float v[3]; float ss = 0.f;
  #pragma unroll
  for (int j=0;j<3;j++){ v[j] = x[threadIdx.x + j*256]; ss += v[j]*v[j]; }
  #pragma unroll
  for (int off=32; off; off>>=1) ss += __shfl_xor(ss, off);
  __shared__ float sred[4];
  int wave = threadIdx.x>>6, lane = threadIdx.x&63;
  if (lane==0) sred[wave]=ss;
  __syncthreads();
  float tot = sred[0]+sred[1]+sred[2]+sred[3];
  float scale = rsqrtf(tot*(1.f/Dm) + EPSf);
  bf16* o = xb + (size_t)t*Dm;
  #pragma unroll
  for (int j=0;j<3;j++){ int d = threadIdx.x + j*256; o[d] = f2b(v[j]*scale*w[d]); }
}

// ---------------- final rmsnorm, last token per batch ------------------------
__global__ __launch_bounds__(256) void k_rms_last(const float* __restrict__ h,
                                                  const float* __restrict__ w,
                                                  float* __restrict__ xf){
  int b = blockIdx.x;
  const float* x = h + ((size_t)b*Sq + (Sq-1))*Dm;
  float v[3]; float ss = 0.f;
  #pragma unroll
  for (int j=0;j<3;j++){ v[j] = x[threadIdx.x + j*256]; ss += v[j]*v[j]; }
  #pragma unroll
  for (int off=32; off; off>>=1) ss += __shfl_xor(ss, off);
  __shared__ float sred[4];
  int wave = threadIdx.x>>6, lane = threadIdx.x&63;
  if (lane==0) sred[wave]=ss;
  __syncthreads();
  float tot = sred[0]+sred[1]+sred[2]+sred[3];
  float scale = rsqrtf(tot*(1.f/Dm) + EPSf);
  float* o = xf + (size_t)b*Dm;
  #pragma unroll
  for (int j=0;j<3;j++){ int d = threadIdx.x + j*256; o[d] = v[j]*scale*w[d]; }
}

// ---------------- MFMA bf16 GEMM: C(M,N) = A(M,K) * B(N,K)^T -----------------
// MODE 0: store bf16 | MODE 1: C_f32 += acc | MODE 3: f32 softplus(acc+bias[col])
template<int MODE>
__global__ __launch_bounds__(256) void k_gemm(const bf16* __restrict__ A,
                                              const bf16* __restrict__ Bw,
                                              void* __restrict__ Cout,
                                              const float* __restrict__ bias,
                                              int M, int N, int K,
                                              int lda, int ldb, int ldc){
  __shared__ __align__(16) ushort Ash[128*32];
  __shared__ __align__(16) ushort Bsh[128*32];
  int tid = threadIdx.x;
  int bm = blockIdx.y, bn = blockIdx.x;
  int wave = tid >> 6, lane = tid & 63;
  int wrow = wave >> 1, wcol = wave & 1;
  int quad = lane >> 4, lq = lane & 15;

  f32x4 acc[4][4];
  #pragma unroll
  for (int a=0;a<4;a++)
    #pragma unroll
    for (int b=0;b<4;b++) acc[a][b] = (f32x4){0.f,0.f,0.f,0.f};

  const ushort* Ag = (const ushort*)A;
  const ushort* Bg = (const ushort*)Bw;

  for (int k0 = 0; k0 < K; k0 += 32) {
    __syncthreads();
    #pragma unroll
    for (int c = tid; c < 512; c += 256) {
      int row = c >> 2, col = (c & 3) * 8;
      *(uint4*)&Ash[row*32 + col] = *(const uint4*)&Ag[(size_t)(bm*128 + row)*lda + k0 + col];
      *(uint4*)&Bsh[row*32 + col] = *(const uint4*)&Bg[(size_t)(bn*128 + row)*ldb + k0 + col];
    }
    __syncthreads();
    bf16x8 af[4], bfr[4];
    #pragma unroll
    for (int a=0;a<4;a++){
      int m = wrow*64 + a*16 + lq;
      af[a] = __builtin_bit_cast(bf16x8, *(const uint4*)&Ash[m*32 + quad*8]);
    }
    #pragma unroll
    for (int b=0;b<4;b++){
      int n = wcol*64 + b*16 + lq;
      bfr[b] = __builtin_bit_cast(bf16x8, *(const uint4*)&Bsh[n*32 + quad*8]);
    }
    #pragma unroll
    for (int a=0;a<4;a++)
      #pragma unroll
      for (int b=0;b<4;b++)
        acc[a][b] = __builtin_amdgcn_mfma_f32_16x16x32_bf16(af[a], bfr[b], acc[a][b], 0, 0, 0);
  }
  // C/D layout (HW-verified gfx950): row = quad*4+reg, col = lane&15
  #pragma unroll
  for (int a=0;a<4;a++)
    #pragma unroll
    for (int b=0;b<4;b++)
      #pragma unroll
      for (int r=0;r<4;r++){
        int row = bm*128 + wrow*64 + a*16 + quad*4 + r;
        int col = bn*128 + wcol*64 + b*16 + lq;
        size_t idx = (size_t)row*ldc + col;
        if (MODE == 0) ((bf16*)Cout)[idx] = f2b(acc[a][b][r]);
        else if (MODE == 1) ((float*)Cout)[idx] += acc[a][b][r];
        else {
          float v = acc[a][b][r] + bias[col];
          ((float*)Cout)[idx] = (v > 20.f) ? v : log1pf(__expf(v));
        }
      }
}

// ---------------- depthwise causal conv K=4 + bias + SiLU --------------------
__global__ __launch_bounds__(256) void k_conv(const bf16* __restrict__ proj,
                                              const float* __restrict__ cw,
                                              const float* __restrict__ cb,
                                              bf16* __restrict__ ut){
  int t = blockIdx.y;
  int i = blockIdx.x*256 + threadIdx.x;
  int s = t & (Sq-1);
  float acc = cb[i];
  #pragma unroll
  for (int k=0;k<Kc;k++){
    int sk = s + k - 3;
    if (sk >= 0) acc += b2f(proj[(size_t)(t+k-3)*(2*Im) + i]) * cw[i*Kc+k];
  }
  float sig = 1.f/(1.f+__expf(-acc));
  ut[(size_t)t*Im + i] = f2b(acc*sig);
}

// ---------------- selective scan, time-tiled through LDS ---------------------
// Block: 256 thr = 16 channels (ci) x 16 states (n). Grid: (Im/16, Bt).
// Per tile of TS=64 steps: prefetch tile t+1 to regs, stage tile t in LDS,
// run recurrence from LDS (broadcast reads), butterfly-reduce y, flush y tile.
#define TS 64
#define CH 16
__global__ __launch_bounds__(256) void k_scan(const float* __restrict__ dt,
                                              const bf16* __restrict__ ut,
                                              const bf16* __restrict__ xdbl,
                                              const bf16* __restrict__ proj,
                                              const float* __restrict__ alog,
                                              const float* __restrict__ dpar,
                                              bf16* __restrict__ y){
  __shared__ float s_dt[TS][CH];                 // 4 KB
  __shared__ bf16  s_u [TS][CH];                 // 2 KB
  __shared__ bf16  s_g [TS][CH];                 // 2 KB
  __shared__ bf16  s_bc[TS][32];                 // 4 KB (B[0..15] | C[0..15])
  __shared__ bf16  s_y [TS][CH];                 // 2 KB
  int tid = threadIdx.x;
  int b   = blockIdx.y;
  int i0  = blockIdx.x*CH;
  int n   = tid & 15, ci = tid >> 4;
  int i   = i0 + ci;
  float A  = -__expf(alog[i*Nst + n]);
  float Dp = dpar[i];
  size_t tok0 = (size_t)b*Sq;

  int row = tid >> 2, part = tid & 3;            // staging role: 64 rows x 4 parts
  float4 p_dt; uint2 p_u, p_g; uint4 p_bc;
  {
    size_t tr = tok0 + row;
    p_dt = *(const float4*)(dt + tr*Im + i0 + part*4);
    p_u  = *(const uint2*)((const ushort*)ut  + tr*Im + i0 + part*4);
    p_g  = *(const uint2*)((const ushort*)proj + tr*2*Im + Im + i0 + part*4);
    p_bc = *(const uint4*)((const ushort*)xdbl + tr*128 + 48 + part*8);
  }

  float h = 0.f;
  for (int t0 = 0; t0 < Sq; t0 += TS){
    __syncthreads();                             // prev tile fully consumed
    *(float4*)&s_dt[row][part*4] = p_dt;
    *(uint2*) &s_u [row][part*4] = p_u;
    *(uint2*) &s_g [row][part*4] = p_g;
    *(uint4*) &s_bc[row][part*8] = p_bc;
    __syncthreads();
    if (t0 + TS < Sq){                           // prefetch next tile (overlaps compute)
      size_t tr = tok0 + t0 + TS + row;
      p_dt = *(const float4*)(dt + tr*Im + i0 + part*4);
      p_u  = *(const uint2*)((const ushort*)ut  + tr*Im + i0 + part*4);
      p_g  = *(const uint2*)((const ushort*)proj + tr*2*Im + Im + i0 + part*4);
      p_bc = *(const uint4*)((const ushort*)xdbl + tr*128 + 48 + part*8);
    }
    #pragma unroll 8
    for (int ts = 0; ts < TS; ts++){
      float dtv = s_dt[ts][ci];
      float uv  = b2f(s_u[ts][ci]);
      float Bn  = b2f(s_bc[ts][n]);
      float Cn  = b2f(s_bc[ts][16+n]);
      float e   = __expf(dtv*A);
      h = e*h + dtv*uv*Bn;
      float p = h*Cn;
      p += __shfl_xor(p,1); p += __shfl_xor(p,2);
      p += __shfl_xor(p,4); p += __shfl_xor(p,8);
      if (n==0){
        float g = b2f(s_g[ts][ci]);
        s_y[ts][ci] = f2b((p + uv*Dp) * (g/(1.f+__expf(-g))));
      }
    }
    __syncthreads();                             // s_y complete
    *(uint2*)((ushort*)y + (tok0 + t0 + row)*Im + i0 + part*4) =
        *(const uint2*)&s_y[row][part*4];
  }
}

// ---------------- logits (f32 out): out[b,v] = xf[b,:] . embed[v,:] ----------
__global__ __launch_bounds__(256) void k_logits(const float* __restrict__ xf,
                                                const float* __restrict__ emb,
                                                float* __restrict__ out){
  __shared__ __align__(16) float xs[Bt*Dm];
  for (int j = threadIdx.x; j < Bt*Dm; j += 256) xs[j] = xf[j];
  __syncthreads();
  int wave = threadIdx.x>>6, lane = threadIdx.x&63;
  int v = blockIdx.x*4 + wave;
  const float4* e4 = (const float4*)(emb + (size_t)v*Dm);
  float a0=0.f,a1=0.f,a2=0.f,a3=0.f;
  for (int j = lane; j < Dm/4; j += 64){
    float4 ev = e4[j];
    float4 x0 = *(const float4*)&xs[j*4];
    float4 x1 = *(const float4*)&xs[Dm + j*4];
    float4 x2 = *(const float4*)&xs[2*Dm + j*4];
    float4 x3 = *(const float4*)&xs[3*Dm + j*4];
    a0 += ev.x*x0.x + ev.y*x0.y + ev.z*x0.z + ev.w*x0.w;
    a1 += ev.x*x1.x + ev.y*x1.y + ev.z*x1.z + ev.w*x1.w;
    a2 += ev.x*x2.x + ev.y*x2.y + ev.z*x2.z + ev.w*x2.w;
    a3 += ev.x*x3.x + ev.y*x3.y + ev.z*x3.z + ev.w*x3.w;
  }
  #pragma unroll
  for (int off=32; off; off>>=1){
    a0+=__shfl_xor(a0,off); a1+=__shfl_xor(a1,off);
    a2+=__shfl_xor(a2,off); a3+=__shfl_xor(a3,off);
  }
  if (lane==0){
    out[v]        = a0;
    out[Vv+v]     = a1;
    out[2*Vv+v]   = a2;
    out[3*Vv+v]   = a3;
  }
}

extern "C" void kernel_launch(void* const* d_in, const int* in_sizes, int n_in,
                              void* d_out, int out_size, void* d_ws, size_t ws_size,
                              hipStream_t stream){
  const int*   ids   = (const int*)d_in[0];
  const float* emb   = (const float*)d_in[1];
  const float* normw = (const float*)d_in[2];
  const float* inw   = (const float*)d_in[3];
  const float* cw    = (const float*)d_in[4];
  const float* cb    = (const float*)d_in[5];
  const float* xpw   = (const float*)d_in[6];
  const float* dtw   = (const float*)d_in[7];
  const float* dtb   = (const float*)d_in[8];
  const float* alog  = (const float*)d_in[9];
  const float* dpar  = (const float*)d_in[10];
  const float* outw  = (const float*)d_in[11];
  const float* normf = (const float*)d_in[12];
  float* out = (float*)d_out;   // reference output dtype is float32

  char* p = (char*)d_ws;
  float* h    = (float*)p;  p += (size_t)TOK*Dm*4;        // 25.2 MB
  bf16*  xb   = (bf16*)p;   p += (size_t)TOK*Dm*2;        // 12.6 MB
  bf16*  proj = (bf16*)p;   p += (size_t)TOK*2*Im*2;      // 50.3 MB  (u | gate)
  bf16*  utb  = (bf16*)p;   p += (size_t)TOK*Im*2;        // 25.2 MB
  bf16*  xdbl = (bf16*)p;   p += (size_t)TOK*128*2;       // 2.1 MB   (dt_r|B|C|pad)
  float* dtf  = (float*)p;  p += (size_t)TOK*Im*4;        // 50.3 MB
  bf16*  yb   = (bf16*)p;   p += (size_t)TOK*Im*2;        // 25.2 MB
  float* xf   = (float*)p;  p += (size_t)Bt*Dm*4;         // 12 KB
  bf16*  inwb = (bf16*)p;   p += (size_t)Lm*2*Im*Dm*2;    // 18.9 MB
  bf16*  outwb= (bf16*)p;   p += (size_t)Lm*Dm*Im*2;      // 9.4 MB
  bf16*  xpwb = (bf16*)p;   p += (size_t)Lm*128*Im*2;     // 1.6 MB
  bf16*  dtwb = (bf16*)p;   p += (size_t)Lm*Im*64*2;      // 0.8 MB (~222 MB total, proven)

  // weight conversions (every call — no static state)
  { int n = Lm*2*Im*Dm; k_cvt<<<n/1024, 256, 0, stream>>>(inw, inwb, n); }
  { int n = Lm*Dm*Im;   k_cvt<<<n/1024, 256, 0, stream>>>(outw, outwb, n); }
  k_cvt_xpw<<<(Lm*128*Im)/256, 256, 0, stream>>>(xpw, xpwb);
  k_cvt_dtw<<<(Lm*Im*64)/256, 256, 0, stream>>>(dtw, dtwb);

  k_embed<<<TOK, 256, 0, stream>>>(ids, emb, h);

  for (int l = 0; l < Lm; l++){
    k_rmsnorm<<<TOK, 256, 0, stream>>>(h, normw + l*Dm, xb);
    // in_proj: proj(TOK,3072) = xb(TOK,768) . inw(3072,768)^T
    k_gemm<0><<<dim3((2*Im)/128, TOK/128), 256, 0, stream>>>(
        xb, inwb + (size_t)l*2*Im*Dm, proj, nullptr, TOK, 2*Im, Dm, Dm, Dm, 2*Im);
    k_conv<<<dim3(Im/256, TOK), 256, 0, stream>>>(
        proj, cw + (size_t)l*Im*Kc, cb + (size_t)l*Im, utb);
    // x_proj: xdbl(TOK,128) = utb(TOK,1536) . xpwb(128,1536)^T (rows 80.. zero)
    k_gemm<0><<<dim3(1, TOK/128), 256, 0, stream>>>(
        utb, xpwb + (size_t)l*128*Im, xdbl, nullptr, TOK, 128, Im, Im, Im, 128);
    // dt_proj+softplus: dtf(TOK,1536) = xdbl(TOK,64) . dtwb(1536,64)^T + dtb
    k_gemm<3><<<dim3(Im/128, TOK/128), 256, 0, stream>>>(
        xdbl, dtwb + (size_t)l*Im*64, dtf, dtb + (size_t)l*Im, TOK, Im, 64, 128, 64, Im);
    k_scan<<<dim3(Im/CH, Bt), 256, 0, stream>>>(
        dtf, utb, xdbl, proj, alog + (size_t)l*Im*Nst, dpar + (size_t)l*Im, yb);
    // out_proj (+residual): h(TOK,768) += yb(TOK,1536) . outw(768,1536)^T
    k_gemm<1><<<dim3(Dm/128, TOK/128), 256, 0, stream>>>(
        yb, outwb + (size_t)l*Dm*Im, h, nullptr, TOK, Dm, Im, Im, Im, Dm);
  }

  k_rms_last<<<Bt, 256, 0, stream>>>(h, normf, xf);
  k_logits<<<Vv/4, 256, 0, stream>>>(xf, emb, out);
}

// Round 7
// 1937.746 us; speedup vs baseline: 3.7785x; 1.7591x over previous
//
#include <hip/hip_runtime.h>
#include <hip/hip_bf16.h>

#define Vv 32000
#define Dm 768
#define Lm 4
#define Nst 16
#define Kc 4
#define Im 1536
#define DTr 48
#define Bt 4
#define Sq 2048
#define TOK (Bt*Sq)
#define EPSf 1e-5f
#define NC 32              // time chunks
#define CL 64              // chunk length = Sq/NC
#define LOG2E 1.4426950408889634f

using bf16 = __hip_bfloat16;
typedef __bf16 bf16x8 __attribute__((ext_vector_type(8)));
typedef float f32x4 __attribute__((ext_vector_type(4)));

__device__ __forceinline__ float b2f(bf16 x){ return __bfloat162float(x); }
__device__ __forceinline__ bf16 f2b(float x){ return __float2bfloat16(x); }
__device__ __forceinline__ float us2f(ushort u){ unsigned x = (unsigned)u << 16; return __builtin_bit_cast(float, x); }

// ---------------- f32 -> bf16 weight conversion (n multiple of 1024) --------
__global__ __launch_bounds__(256) void k_cvt(const float* __restrict__ src,
                                             bf16* __restrict__ dst, int n){
  int i = (blockIdx.x*256 + threadIdx.x)*4;
  if (i >= n) return;
  float4 v = *(const float4*)(src + i);
  bf16* o = dst + i;
  o[0]=f2b(v.x); o[1]=f2b(v.y); o[2]=f2b(v.z); o[3]=f2b(v.w);
}

// x_proj_w (L,80,Im) f32 -> (L,128,Im) bf16, rows 80..127 zero
__global__ __launch_bounds__(256) void k_cvt_xpw(const float* __restrict__ src,
                                                 bf16* __restrict__ dst){
  int idx = blockIdx.x*256 + threadIdx.x;
  int l = idx / (128*Im); int rem = idx - l*128*Im;
  int r = rem / Im;       int c = rem - r*Im;
  dst[idx] = (r < 80) ? f2b(src[((size_t)l*80 + r)*Im + c]) : f2b(0.f);
}

// dt_proj_w (L,Im,48) f32 -> (L,Im,64) bf16, cols 48..63 zero
__global__ __launch_bounds__(256) void k_cvt_dtw(const float* __restrict__ src,
                                                 bf16* __restrict__ dst){
  int idx = blockIdx.x*256 + threadIdx.x;
  int l = idx / (Im*64); int rem = idx - l*Im*64;
  int r = rem / 64;      int c = rem - r*64;
  dst[idx] = (c < 48) ? f2b(src[((size_t)l*Im + r)*48 + c]) : f2b(0.f);
}

// ---------------- embedding gather ------------------------------------------
__global__ __launch_bounds__(256) void k_embed(const int* __restrict__ ids,
                                               const float* __restrict__ emb,
                                               float* __restrict__ h){
  int t = blockIdx.x;
  const float4* e = (const float4*)(emb + (size_t)ids[t]*Dm);
  float4* o = (float4*)(h + (size_t)t*Dm);
  if (threadIdx.x < Dm/4) o[threadIdx.x] = e[threadIdx.x];
}

// ---------------- rmsnorm ---------------------------------------------------
__global__ __launch_bounds__(256) void k_rmsnorm(const float* __restrict__ h,
                                                 const float* __restrict__ w,
                                                 bf16* __restrict__ xb){
  int t = blockIdx.x;
  const float* x = h + (size_t)t*Dm;
  float v[3]; float ss = 0.f;
  #pragma unroll
  for (int j=0;j<3;j++){ v[j] = x[threadIdx.x + j*256]; ss += v[j]*v[j]; }
  #pragma unroll
  for (int off=32; off; off>>=1) ss += __shfl_xor(ss, off);
  __shared__ float sred[4];
  int wave = threadIdx.x>>6, lane = threadIdx.x&63;
  if (lane==0) sred[wave]=ss;
  __syncthreads();
  float tot = sred[0]+sred[1]+sred[2]+sred[3];
  float scale = rsqrtf(tot*(1.f/Dm) + EPSf);
  bf16* o = xb + (size_t)t*Dm;
  #pragma unroll
  for (int j=0;j<3;j++){ int d = threadIdx.x + j*256; o[d] = f2b(v[j]*scale*w[d]); }
}

__global__ __launch_bounds__(256) void k_rms_last(const float* __restrict__ h,
                                                  const float* __restrict__ w,
                                                  float* __restrict__ xf){
  int b = blockIdx.x;
  const float* x = h + ((size_t)b*Sq + (Sq-1))*Dm;
  float v[3]; float ss = 0.f;
  #pragma unroll
  for (int j=0;j<3;j++){ v[j] = x[threadIdx.x + j*256]; ss += v[j]*v[j]; }
  #pragma unroll
  for (int off=32; off; off>>=1) ss += __shfl_xor(ss, off);
  __shared__ float sred[4];
  int wave = threadIdx.x>>6, lane = threadIdx.x&63;
  if (lane==0) sred[wave]=ss;
  __syncthreads();
  float tot = sred[0]+sred[1]+sred[2]+sred[3];
  float scale = rsqrtf(tot*(1.f/Dm) + EPSf);
  float* o = xf + (size_t)b*Dm;
  #pragma unroll
  for (int j=0;j<3;j++){ int d = threadIdx.x + j*256; o[d] = v[j]*scale*w[d]; }
}

// ---------------- MFMA bf16 GEMM: C(M,N) = A(M,K) * B(N,K)^T -----------------
template<int MODE>
__global__ __launch_bounds__(256) void k_gemm(const bf16* __restrict__ A,
                                              const bf16* __restrict__ Bw,
                                              void* __restrict__ Cout,
                                              const float* __restrict__ bias,
                                              int M, int N, int K,
                                              int lda, int ldb, int ldc){
  __shared__ __align__(16) ushort Ash[128*32];
  __shared__ __align__(16) ushort Bsh[128*32];
  int tid = threadIdx.x;
  int bm = blockIdx.y, bn = blockIdx.x;
  int wave = tid >> 6, lane = tid & 63;
  int wrow = wave >> 1, wcol = wave & 1;
  int quad = lane >> 4, lq = lane & 15;

  f32x4 acc[4][4];
  #pragma unroll
  for (int a=0;a<4;a++)
    #pragma unroll
    for (int b=0;b<4;b++) acc[a][b] = (f32x4){0.f,0.f,0.f,0.f};

  const ushort* Ag = (const ushort*)A;
  const ushort* Bg = (const ushort*)Bw;

  for (int k0 = 0; k0 < K; k0 += 32) {
    __syncthreads();
    #pragma unroll
    for (int c = tid; c < 512; c += 256) {
      int row = c >> 2, col = (c & 3) * 8;
      *(uint4*)&Ash[row*32 + col] = *(const uint4*)&Ag[(size_t)(bm*128 + row)*lda + k0 + col];
      *(uint4*)&Bsh[row*32 + col] = *(const uint4*)&Bg[(size_t)(bn*128 + row)*ldb + k0 + col];
    }
    __syncthreads();
    bf16x8 af[4], bfr[4];
    #pragma unroll
    for (int a=0;a<4;a++){
      int m = wrow*64 + a*16 + lq;
      af[a] = __builtin_bit_cast(bf16x8, *(const uint4*)&Ash[m*32 + quad*8]);
    }
    #pragma unroll
    for (int b=0;b<4;b++){
      int n = wcol*64 + b*16 + lq;
      bfr[b] = __builtin_bit_cast(bf16x8, *(const uint4*)&Bsh[n*32 + quad*8]);
    }
    #pragma unroll
    for (int a=0;a<4;a++)
      #pragma unroll
      for (int b=0;b<4;b++)
        acc[a][b] = __builtin_amdgcn_mfma_f32_16x16x32_bf16(af[a], bfr[b], acc[a][b], 0, 0, 0);
  }
  #pragma unroll
  for (int a=0;a<4;a++)
    #pragma unroll
    for (int b=0;b<4;b++)
      #pragma unroll
      for (int r=0;r<4;r++){
        int row = bm*128 + wrow*64 + a*16 + quad*4 + r;
        int col = bn*128 + wcol*64 + b*16 + lq;
        size_t idx = (size_t)row*ldc + col;
        if (MODE == 0) ((bf16*)Cout)[idx] = f2b(acc[a][b][r]);
        else if (MODE == 1) ((float*)Cout)[idx] += acc[a][b][r];
        else {
          float v = acc[a][b][r] + bias[col];
          ((float*)Cout)[idx] = (v > 20.f) ? v : log1pf(__expf(v));
        }
      }
}

// ---------------- depthwise causal conv K=4 + bias + SiLU --------------------
__global__ __launch_bounds__(256) void k_conv(const bf16* __restrict__ proj,
                                              const float* __restrict__ cw,
                                              const float* __restrict__ cb,
                                              bf16* __restrict__ ut){
  int t = blockIdx.y;
  int i = blockIdx.x*256 + threadIdx.x;
  int s = t & (Sq-1);
  float acc = cb[i];
  #pragma unroll
  for (int k=0;k<Kc;k++){
    int sk = s + k - 3;
    if (sk >= 0) acc += b2f(proj[(size_t)(t+k-3)*(2*Im) + i]) * cw[i*Kc+k];
  }
  float sig = 1.f/(1.f+__expf(-acc));
  ut[(size_t)t*Im + i] = f2b(acc*sig);
}

// ============ chunked selective scan: thread per (b,i,chunk), 16 states/thread
// Q, Hin live in the DEAD u-columns of proj (rows < 4096, cols [0,Im)).

// pass1: per-chunk local scan from h=0 -> Q (h_end, bf16), S (sum dt, f32)
__global__ __launch_bounds__(256) void k_scan1(const float* __restrict__ dt,
                                               const bf16* __restrict__ ut,
                                               const bf16* __restrict__ xdbl,
                                               const float* __restrict__ alog,
                                               bf16* __restrict__ Qb,   // proj base
                                               float* __restrict__ S){
  __shared__ float s_b[CL][16];                  // 4 KB: B per step
  int tid = threadIdx.x;
  int i = blockIdx.x*256 + tid;
  int b = blockIdx.y, c = blockIdx.z;
  size_t tok0 = (size_t)b*Sq + c*CL;
  // stage B (cols 48..63 of xdbl) as f32
  {
    int row = tid >> 1, part = tid & 1;          // 128 slots >= CL*2
    if (row < CL){
      uint4 v = *(const uint4*)((const ushort*)xdbl + (tok0+row)*128 + 48 + part*8);
      const ushort* u = (const ushort*)&v;
      #pragma unroll
      for (int j=0;j<8;j++) s_b[row][part*8+j] = us2f(u[j]);
    }
  }
  float kn[16];
  {
    const float4* ap = (const float4*)(alog + (size_t)i*16);
    #pragma unroll
    for (int q=0;q<4;q++){
      float4 a4 = ap[q];
      kn[q*4+0] = -__expf(a4.x)*LOG2E; kn[q*4+1] = -__expf(a4.y)*LOG2E;
      kn[q*4+2] = -__expf(a4.z)*LOG2E; kn[q*4+3] = -__expf(a4.w)*LOG2E;
    }
  }
  __syncthreads();
  float h[16];
  #pragma unroll
  for (int n=0;n<16;n++) h[n]=0.f;
  float sum = 0.f;
  float dtn = dt[tok0*Im + i];
  ushort un = ((const ushort*)ut)[tok0*Im + i];
  for (int t = 0; t < CL; t++){
    float dtv = dtn; float uv = us2f(un);
    if (t+1 < CL){
      dtn = dt[(tok0+t+1)*Im + i];
      un  = ((const ushort*)ut)[(tok0+t+1)*Im + i];
    }
    sum += dtv;
    float cdu = dtv*uv;
    const f32x4* brow = (const f32x4*)&s_b[t][0];
    f32x4 B0=brow[0], B1=brow[1], B2=brow[2], B3=brow[3];
    float Bv[16] = {B0[0],B0[1],B0[2],B0[3],B1[0],B1[1],B1[2],B1[3],
                    B2[0],B2[1],B2[2],B2[3],B3[0],B3[1],B3[2],B3[3]};
    #pragma unroll
    for (int n=0;n<16;n++)
      h[n] = exp2f(kn[n]*dtv)*h[n] + cdu*Bv[n];
  }
  int rq = (b*NC + c)*16;
  S[(size_t)(b*NC + c)*Im + i] = sum;
  #pragma unroll
  for (int n=0;n<16;n++)
    Qb[(size_t)(rq+n)*2*Im + i] = f2b(h[n]);
}

// pass2: stitch chunks: Hin[c] = h before chunk c
__global__ __launch_bounds__(256) void k_scan2(const bf16* __restrict__ Qb,
                                               const float* __restrict__ S,
                                               const float* __restrict__ alog,
                                               bf16* __restrict__ Hinb){
  int idx = blockIdx.x*256 + threadIdx.x;        // (b,n,i)
  int i = idx % Im; int bn = idx / Im;
  int n = bn & 15, b = bn >> 4;
  float kn = -__expf(alog[(size_t)i*16 + n])*LOG2E;
  float h = 0.f;
  for (int c = 0; c < NC; c++){
    size_t r = (size_t)((b*NC + c)*16 + n);
    Hinb[(2048 + r)*2*Im + i] = f2b(h);
    float P = exp2f(kn * S[(size_t)(b*NC + c)*Im + i]);
    h = P*h + b2f(Qb[r*2*Im + i]);
  }
}

// pass3: re-run chunk with h_in, produce y with fused epilogue
__global__ __launch_bounds__(256) void k_scan3(const float* __restrict__ dt,
                                               const bf16* __restrict__ ut,
                                               const bf16* __restrict__ xdbl,
                                               const bf16* __restrict__ proj,
                                               const float* __restrict__ alog,
                                               const float* __restrict__ dpar,
                                               const bf16* __restrict__ Hinb,
                                               bf16* __restrict__ y){
  __shared__ float s_bc[CL][32];                 // 8 KB: B|C per step
  int tid = threadIdx.x;
  int i = blockIdx.x*256 + tid;
  int b = blockIdx.y, c = blockIdx.z;
  size_t tok0 = (size_t)b*Sq + c*CL;
  {
    int row = tid >> 1, part = tid & 1;
    if (row < CL){
      const ushort* src = (const ushort*)xdbl + (tok0+row)*128 + 48 + part*16;
      uint4 v0 = *(const uint4*)src;
      uint4 v1 = *(const uint4*)(src + 8);
      const ushort* u0 = (const ushort*)&v0;
      const ushort* u1 = (const ushort*)&v1;
      #pragma unroll
      for (int j=0;j<8;j++){
        s_bc[row][part*16 + j]     = us2f(u0[j]);
        s_bc[row][part*16 + 8 + j] = us2f(u1[j]);
      }
    }
  }
  float kn[16];
  {
    const float4* ap = (const float4*)(alog + (size_t)i*16);
    #pragma unroll
    for (int q=0;q<4;q++){
      float4 a4 = ap[q];
      kn[q*4+0] = -__expf(a4.x)*LOG2E; kn[q*4+1] = -__expf(a4.y)*LOG2E;
      kn[q*4+2] = -__expf(a4.z)*LOG2E; kn[q*4+3] = -__expf(a4.w)*LOG2E;
    }
  }
  float Dp = dpar[i];
  float h[16];
  {
    int rq = 2048 + (b*NC + c)*16;
    #pragma unroll
    for (int n=0;n<16;n++)
      h[n] = b2f(Hinb[(size_t)(rq+n)*2*Im + i]);
  }
  __syncthreads();
  float dtn = dt[tok0*Im + i];
  ushort un = ((const ushort*)ut)[tok0*Im + i];
  ushort gn = ((const ushort*)proj)[tok0*2*Im + Im + i];
  for (int t = 0; t < CL; t++){
    float dtv = dtn; float uv = us2f(un); float g = us2f(gn);
    if (t+1 < CL){
      dtn = dt[(tok0+t+1)*Im + i];
      un  = ((const ushort*)ut)[(tok0+t+1)*Im + i];
      gn  = ((const ushort*)proj)[(tok0+t+1)*2*Im + Im + i];
    }
    float cdu = dtv*uv;
    const f32x4* brow = (const f32x4*)&s_bc[t][0];
    f32x4 B0=brow[0], B1=brow[1], B2=brow[2], B3=brow[3];
    f32x4 C0=brow[4], C1=brow[5], C2=brow[6], C3=brow[7];
    float Bv[16] = {B0[0],B0[1],B0[2],B0[3],B1[0],B1[1],B1[2],B1[3],
                    B2[0],B2[1],B2[2],B2[3],B3[0],B3[1],B3[2],B3[3]};
    float Cv[16] = {C0[0],C0[1],C0[2],C0[3],C1[0],C1[1],C1[2],C1[3],
                    C2[0],C2[1],C2[2],C2[3],C3[0],C3[1],C3[2],C3[3]};
    float yv = 0.f;
    #pragma unroll
    for (int n=0;n<16;n++){
      h[n] = exp2f(kn[n]*dtv)*h[n] + cdu*Bv[n];
      yv += h[n]*Cv[n];
    }
    float out = (yv + uv*Dp) * (g/(1.f+__expf(-g)));
    y[(tok0+t)*Im + i] = f2b(out);
  }
}

// ---------------- logits (f32 out) ------------------------------------------
__global__ __launch_bounds__(256) void k_logits(const float* __restrict__ xf,
                                                const float* __restrict__ emb,
                                                float* __restrict__ out){
  __shared__ __align__(16) float xs[Bt*Dm];
  for (int j = threadIdx.x; j < Bt*Dm; j += 256) xs[j] = xf[j];
  __syncthreads();
  int wave = threadIdx.x>>6, lane = threadIdx.x&63;
  int v = blockIdx.x*4 + wave;
  const float4* e4 = (const float4*)(emb + (size_t)v*Dm);
  float a0=0.f,a1=0.f,a2=0.f,a3=0.f;
  for (int j = lane; j < Dm/4; j += 64){
    float4 ev = e4[j];
    float4 x0 = *(const float4*)&xs[j*4];
    float4 x1 = *(const float4*)&xs[Dm + j*4];
    float4 x2 = *(const float4*)&xs[2*Dm + j*4];
    float4 x3 = *(const float4*)&xs[3*Dm + j*4];
    a0 += ev.x*x0.x + ev.y*x0.y + ev.z*x0.z + ev.w*x0.w;
    a1 += ev.x*x1.x + ev.y*x1.y + ev.z*x1.z + ev.w*x1.w;
    a2 += ev.x*x2.x + ev.y*x2.y + ev.z*x2.z + ev.w*x2.w;
    a3 += ev.x*x3.x + ev.y*x3.y + ev.z*x3.z + ev.w*x3.w;
  }
  #pragma unroll
  for (int off=32; off; off>>=1){
    a0+=__shfl_xor(a0,off); a1+=__shfl_xor(a1,off);
    a2+=__shfl_xor(a2,off); a3+=__shfl_xor(a3,off);
  }
  if (lane==0){
    out[v]        = a0;
    out[Vv+v]     = a1;
    out[2*Vv+v]   = a2;
    out[3*Vv+v]   = a3;
  }
}

extern "C" void kernel_launch(void* const* d_in, const int* in_sizes, int n_in,
                              void* d_out, int out_size, void* d_ws, size_t ws_size,
                              hipStream_t stream){
  const int*   ids   = (const int*)d_in[0];
  const float* emb   = (const float*)d_in[1];
  const float* normw = (const float*)d_in[2];
  const float* inw   = (const float*)d_in[3];
  const float* cw    = (const float*)d_in[4];
  const float* cb    = (const float*)d_in[5];
  const float* xpw   = (const float*)d_in[6];
  const float* dtw   = (const float*)d_in[7];
  const float* dtb   = (const float*)d_in[8];
  const float* alog  = (const float*)d_in[9];
  const float* dpar  = (const float*)d_in[10];
  const float* outw  = (const float*)d_in[11];
  const float* normf = (const float*)d_in[12];
  float* out = (float*)d_out;

  char* p = (char*)d_ws;
  float* h    = (float*)p;  p += (size_t)TOK*Dm*4;        // 25.2 MB
  bf16*  xb   = (bf16*)p;   p += (size_t)TOK*Dm*2;        // 12.6 MB (S aliases tail)
  bf16*  proj = (bf16*)p;   p += (size_t)TOK*2*Im*2;      // 50.3 MB (u|gate; Q/Hin in u cols)
  bf16*  utb  = (bf16*)p;   p += (size_t)TOK*Im*2;        // 25.2 MB
  bf16*  xdbl = (bf16*)p;   p += (size_t)TOK*128*2;       // 2.1 MB
  float* dtf  = (float*)p;  p += (size_t)TOK*Im*4;        // 50.3 MB
  bf16*  yb   = (bf16*)p;   p += (size_t)TOK*Im*2;        // 25.2 MB
  float* xf   = (float*)p;  p += (size_t)Bt*Dm*4;
  bf16*  inwb = (bf16*)p;   p += (size_t)Lm*2*Im*Dm*2;
  bf16*  outwb= (bf16*)p;   p += (size_t)Lm*Dm*Im*2;
  bf16*  xpwb = (bf16*)p;   p += (size_t)Lm*128*Im*2;
  bf16*  dtwb = (bf16*)p;   p += (size_t)Lm*Im*64*2;      // ~222 MB total (proven)
  // scan scratch: S (f32, 786 KB) aliases xb (dead during scan)
  float* S = (float*)xb;

  { int n = Lm*2*Im*Dm; k_cvt<<<n/1024, 256, 0, stream>>>(inw, inwb, n); }
  { int n = Lm*Dm*Im;   k_cvt<<<n/1024, 256, 0, stream>>>(outw, outwb, n); }
  k_cvt_xpw<<<(Lm*128*Im)/256, 256, 0, stream>>>(xpw, xpwb);
  k_cvt_dtw<<<(Lm*Im*64)/256, 256, 0, stream>>>(dtw, dtwb);

  k_embed<<<TOK, 256, 0, stream>>>(ids, emb, h);

  for (int l = 0; l < Lm; l++){
    k_rmsnorm<<<TOK, 256, 0, stream>>>(h, normw + l*Dm, xb);
    k_gemm<0><<<dim3((2*Im)/128, TOK/128), 256, 0, stream>>>(
        xb, inwb + (size_t)l*2*Im*Dm, proj, nullptr, TOK, 2*Im, Dm, Dm, Dm, 2*Im);
    k_conv<<<dim3(Im/256, TOK), 256, 0, stream>>>(
        proj, cw + (size_t)l*Im*Kc, cb + (size_t)l*Im, utb);
    k_gemm<0><<<dim3(1, TOK/128), 256, 0, stream>>>(
        utb, xpwb + (size_t)l*128*Im, xdbl, nullptr, TOK, 128, Im, Im, Im, 128);
    k_gemm<3><<<dim3(Im/128, TOK/128), 256, 0, stream>>>(
        xdbl, dtwb + (size_t)l*Im*64, dtf, dtb + (size_t)l*Im, TOK, Im, 64, 128, 64, Im);
    // chunked scan (Q rows [0,2048), Hin rows [2048,4096) in proj u-columns)
    k_scan1<<<dim3(Im/256, Bt, NC), 256, 0, stream>>>(
        dtf, utb, xdbl, alog + (size_t)l*Im*Nst, proj, S);
    k_scan2<<<(Bt*Nst*Im)/256, 256, 0, stream>>>(
        proj, S, alog + (size_t)l*Im*Nst, proj);
    k_scan3<<<dim3(Im/256, Bt, NC), 256, 0, stream>>>(
        dtf, utb, xdbl, proj, alog + (size_t)l*Im*Nst, dpar + (size_t)l*Im, proj, yb);
    k_gemm<1><<<dim3(Dm/128, TOK/128), 256, 0, stream>>>(
        yb, outwb + (size_t)l*Dm*Im, h, nullptr, TOK, Dm, Im, Im, Im, Dm);
  }

  k_rms_last<<<Bt, 256, 0, stream>>>(h, normf, xf);
  k_logits<<<Vv/4, 256, 0, stream>>>(xf, emb, out);
}